// Round 8
// baseline (218.534 us; speedup 1.0000x reference)
//
#include <hip/hip_runtime.h>
#include <hip/hip_bf16.h>

#define HEADS 8
#define HIDDEN 32
#define DF 256   // D_FEAT
#define HD 256   // HEADS*HIDDEN
#define DCAP 64  // per-node cached-edge cap (Poisson(16) => deg<=64 w.h.p.; fallback covers rest)

typedef __attribute__((ext_vector_type(8))) short short8;
typedef __attribute__((ext_vector_type(4))) float floatx4;

__device__ __forceinline__ ushort bfcvt(float v) {
  return __builtin_bit_cast(ushort, __float2bfloat16(v));
}
__device__ __forceinline__ float bf2f(ushort b) {
  return __uint_as_float(((uint)b) << 16);
}

// ---------------- prep: Wt_bf16[n][k] = bf16(W[k][n]); Lt_bf16[c][k] = bf16(lin_W[k][c]) ----------------
__global__ void prep_kernel(const float* __restrict__ W, const float* __restrict__ lin_W,
                            ushort* __restrict__ Wt, ushort* __restrict__ Lt) {
  int b = blockIdx.x;
  if (b < DF) {
    int k = b, n = threadIdx.x;
    Wt[n * DF + k] = bfcvt(W[k * HD + n]);
  } else {
    int c = b - DF, k = threadIdx.x;
    Lt[c * DF + k] = bfcvt(lin_W[k * HIDDEN + c]);
  }
}

// ---------------- GEMM: Fb(bf16) = x @ W via split-bf16 MFMA, fused el/er ----------------
// BM=64, BN=256, BK=64. 4 waves; wave w: rows mh*32..+31, cols nh*128..+127.
__global__ __launch_bounds__(256) void gemm_mfma_kernel(
    const float* __restrict__ X, const ushort* __restrict__ Wt,
    const float* __restrict__ attn_l, const float* __restrict__ attn_r,
    ushort* __restrict__ Fb, float* __restrict__ el, float* __restrict__ er,
    int M) {
  __shared__ __align__(16) ushort Ahi[64 * 64];
  __shared__ __align__(16) ushort Alo[64 * 64];
  __shared__ __align__(16) ushort Bt[256 * 64];

  int t = threadIdx.x;
  int w = t >> 6, l = t & 63;
  int mh = w & 1, nh = w >> 1;
  int bm = blockIdx.x * 64;

  floatx4 acc[2][8];
#pragma unroll
  for (int i = 0; i < 2; i++)
#pragma unroll
    for (int j = 0; j < 8; j++) acc[i][j] = (floatx4)(0.f);

  for (int k0 = 0; k0 < DF; k0 += 64) {
    // ---- stage A (64 rows x 64 k, f32 -> hi/lo bf16 via hw cvt) ----
#pragma unroll
    for (int q = 0; q < 4; q++) {
      int chunk = q * 256 + t;
      int row = chunk >> 4;
      int c = chunk & 15;
      float4 v;
      if (bm + row < M) v = *(const float4*)(X + (size_t)(bm + row) * DF + k0 + c * 4);
      else v = make_float4(0.f, 0.f, 0.f, 0.f);
      ushort h0 = bfcvt(v.x), h1 = bfcvt(v.y), h2 = bfcvt(v.z), h3 = bfcvt(v.w);
      ushort l0 = bfcvt(v.x - bf2f(h0));
      ushort l1 = bfcvt(v.y - bf2f(h1));
      ushort l2 = bfcvt(v.z - bf2f(h2));
      ushort l3 = bfcvt(v.w - bf2f(h3));
      int s = c >> 1, half = c & 1;
      int off = row * 64 + ((s ^ (row & 7)) << 3) + half * 4;
      ushort4 hv; hv.x = h0; hv.y = h1; hv.z = h2; hv.w = h3;
      ushort4 lv; lv.x = l0; lv.y = l1; lv.z = l2; lv.w = l3;
      *(ushort4*)&Ahi[off] = hv;
      *(ushort4*)&Alo[off] = lv;
    }
    // ---- stage B (256 n-rows x 64 k bf16 from Wt) ----
#pragma unroll
    for (int q = 0; q < 8; q++) {
      int chunk = q * 256 + t;
      int n = chunk >> 3;
      int c = chunk & 7;
      short8 v = *(const short8*)(Wt + (size_t)n * DF + k0 + c * 8);
      *(short8*)&Bt[n * 64 + ((c ^ (n & 7)) << 3)] = v;
    }
    __syncthreads();
    int g = l >> 4;
    int fr = l & 15;
#pragma unroll
    for (int kc = 0; kc < 2; kc++) {
      short8 ah[2], al2[2], bfr[8];
#pragma unroll
      for (int mf = 0; mf < 2; mf++) {
        int row = mh * 32 + mf * 16 + fr;
        int s = (kc * 4 + g) ^ (row & 7);
        ah[mf] = *(const short8*)&Ahi[row * 64 + (s << 3)];
        al2[mf] = *(const short8*)&Alo[row * 64 + (s << 3)];
      }
#pragma unroll
      for (int nf = 0; nf < 8; nf++) {
        int n = nh * 128 + nf * 16 + fr;
        int s = (kc * 4 + g) ^ (n & 7);
        bfr[nf] = *(const short8*)&Bt[n * 64 + (s << 3)];
      }
#pragma unroll
      for (int mf = 0; mf < 2; mf++)
#pragma unroll
        for (int nf = 0; nf < 8; nf++) {
          acc[mf][nf] = __builtin_amdgcn_mfma_f32_16x16x32_bf16(ah[mf], bfr[nf], acc[mf][nf], 0, 0, 0);
          acc[mf][nf] = __builtin_amdgcn_mfma_f32_16x16x32_bf16(al2[mf], bfr[nf], acc[mf][nf], 0, 0, 0);
        }
    }
    __syncthreads();
  }

  int fr = l & 15, fq = l >> 4;
  // ---- fused el/er epilogue: wave covers 4 full heads (nh*4..+3) x 32 rows ----
  {
    float al[8], ar8[8];
#pragma unroll
    for (int nf = 0; nf < 8; ++nf) {
      al[nf] = attn_l[nh * 128 + nf * 16 + fr];
      ar8[nf] = attn_r[nh * 128 + nf * 16 + fr];
    }
#pragma unroll
    for (int mf = 0; mf < 2; ++mf)
#pragma unroll
      for (int r = 0; r < 4; ++r)
#pragma unroll
        for (int p = 0; p < 4; ++p) {
          float vl = acc[mf][2 * p][r] * al[2 * p] + acc[mf][2 * p + 1][r] * al[2 * p + 1];
          float vr = acc[mf][2 * p][r] * ar8[2 * p] + acc[mf][2 * p + 1][r] * ar8[2 * p + 1];
#pragma unroll
          for (int off = 1; off < 16; off <<= 1) {
            vl += __shfl_xor(vl, off, 16);
            vr += __shfl_xor(vr, off, 16);
          }
          int row = bm + mh * 32 + mf * 16 + fq * 4 + r;
          if (fr == 0 && row < M) {
            el[row * HEADS + nh * 4 + p] = vl;
            er[row * HEADS + nh * 4 + p] = vr;
          }
        }
  }
  // ---- C write: col=l&15, row=(l>>4)*4+r ----
#pragma unroll
  for (int mf = 0; mf < 2; mf++) {
#pragma unroll
    for (int nf = 0; nf < 8; nf++) {
      int col = nh * 128 + nf * 16 + fr;
#pragma unroll
      for (int r = 0; r < 4; r++) {
        int row = bm + mh * 32 + mf * 16 + fq * 4 + r;
        if (row < M) Fb[(size_t)row * HD + col] = bfcvt(acc[mf][nf][r]);
      }
    }
  }
}

// ---------------- CSR build ----------------
__global__ void hist_kernel(const int* __restrict__ dst, int* __restrict__ cnt, int E) {
  int e = blockIdx.x * blockDim.x + threadIdx.x;
  if (e < E) atomicAdd(&cnt[dst[e]], 1);
}

__global__ __launch_bounds__(1024) void scan1_kernel(
    const int* __restrict__ cnt, int* __restrict__ rowptr,
    int* __restrict__ partials, int N) {
  __shared__ int buf[1024];
  int b = blockIdx.x, t = threadIdx.x;
  int i = b * 1024 + t;
  int v = (i < N) ? cnt[i] : 0;
  buf[t] = v;
  __syncthreads();
  for (int off = 1; off < 1024; off <<= 1) {
    int x = (t >= off) ? buf[t - off] : 0;
    __syncthreads();
    buf[t] += x;
    __syncthreads();
  }
  int incl = buf[t];
  if (i < N) rowptr[i] = incl - v;  // exclusive
  if (t == 1023) partials[b] = incl;
}

__global__ void scan2_kernel(int* __restrict__ partials, int* __restrict__ rowptr,
                             int nchunks, int N, int E) {
  int t = threadIdx.x;  // 64 threads, 1 block
  if (nchunks <= 64) {
    int v = (t < nchunks) ? partials[t] : 0;
    int incl = v;
#pragma unroll
    for (int off = 1; off < 64; off <<= 1) {
      int x = __shfl_up(incl, off, 64);
      if (t >= off) incl += x;
    }
    if (t < nchunks) partials[t] = incl - v;
  } else if (t == 0) {
    int sum = 0;
    for (int b = 0; b < nchunks; b++) {
      int v = partials[b];
      partials[b] = sum;
      sum += v;
    }
  }
  if (t == 0) rowptr[N] = E;
}

__global__ void scan3_kernel(int* __restrict__ rowptr, const int* __restrict__ partials, int N) {
  int i = blockIdx.x * blockDim.x + threadIdx.x;
  if (i < N) rowptr[i] += partials[i >> 10];
}

__global__ void fill_kernel(const int* __restrict__ src, const int* __restrict__ dst,
                            const int* __restrict__ rowptr, int* __restrict__ cur,
                            int* __restrict__ csr, int E) {
  int e = blockIdx.x * blockDim.x + threadIdx.x;
  if (e < E) {
    int d = dst[e];
    int p = atomicAdd(&cur[d], 1);
    csr[rowptr[d] + p] = src[e];
  }
}

// ---------------- aggregate: 2 waves per node, edge-split gather ----------------
// Block = 256 threads = 4 waves = 2 nodes. Node owned by wave pair; q = wave parity.
// Pass A: 16 sub-lanes/head (8 per wave) compute w=exp(leaky(e)) into shared LDS cache.
// Pass B: wave q aggregates edges [q*hl, q*hl+hl) over all 256 cols; partials combined via LDS.
__global__ __launch_bounds__(256) void aggregate_kernel(
    const uint2* __restrict__ F2, const float* __restrict__ el,
    const float* __restrict__ er, const int* __restrict__ rowptr,
    const int* __restrict__ csr, const float4* __restrict__ bias4,
    ushort* __restrict__ RstB, int N) {
  __shared__ float w_lds[2][DCAP][HEADS];
  __shared__ int s_lds[2][DCAP];
  __shared__ float ssum_lds[2][2][HEADS];
  __shared__ float acc_lds[2][64][4];
  int wv = threadIdx.x >> 6, l = threadIdx.x & 63;
  int node = wv >> 1, q = wv & 1;
  int n = blockIdx.x * 2 + node;
  bool active = (n < N);
  int h = l >> 3, sub = l & 7;
  int start = 0, deg = 0;
  float ern = 0.f;
  if (active) {
    start = rowptr[n];
    deg = rowptr[n + 1] - start;
    ern = er[n * HEADS + h];
  }

  // ---- pass A (edge-slots q*8+sub, stride 16) ----
  float ssum = 0.f;
  for (int idx = q * 8 + sub; idx < deg; idx += 16) {
    int s = csr[start + idx];
    float e = el[s * HEADS + h] + ern;
    e = fmaxf(e, 0.2f * e);  // LeakyReLU(0.2)
    float wgt = __expf(e);   // no max-shift: |e| small for this data, exp-safe
    ssum += wgt;
    if (idx < DCAP) {
      w_lds[node][idx][h] = wgt;
      if (h == 0) s_lds[node][idx] = s;
    }
  }
#pragma unroll
  for (int off = 1; off < 8; off <<= 1) ssum += __shfl_xor(ssum, off, 8);
  if (sub == 0) ssum_lds[node][q][h] = ssum;
  __syncthreads();
  float total = ssum_lds[node][0][h] + ssum_lds[node][1][h];
  float rn = (total > 0.f) ? 1.0f / total : 0.f;

  // ---- pass B: wave q takes contiguous half of [0, lim) ----
  float4 acc = make_float4(0.f, 0.f, 0.f, 0.f);
  int lim = deg < DCAP ? deg : DCAP;
  int hl = (lim + 1) >> 1;
  int b0 = q * hl;
  int b1 = b0 + hl < lim ? b0 + hl : lim;
  int idx = b0;
  for (; idx + 4 <= b1; idx += 4) {
    int s0 = s_lds[node][idx], s1 = s_lds[node][idx + 1];
    int s2 = s_lds[node][idx + 2], s3 = s_lds[node][idx + 3];
    float w0 = w_lds[node][idx][h], w1 = w_lds[node][idx + 1][h];
    float w2 = w_lds[node][idx + 2][h], w3 = w_lds[node][idx + 3][h];
    uint2 u0 = F2[(size_t)s0 * 64 + l];
    uint2 u1 = F2[(size_t)s1 * 64 + l];
    uint2 u2 = F2[(size_t)s2 * 64 + l];
    uint2 u3 = F2[(size_t)s3 * 64 + l];
    acc.x = fmaf(w0, __uint_as_float(u0.x << 16), acc.x);
    acc.y = fmaf(w0, __uint_as_float(u0.x & 0xffff0000u), acc.y);
    acc.z = fmaf(w0, __uint_as_float(u0.y << 16), acc.z);
    acc.w = fmaf(w0, __uint_as_float(u0.y & 0xffff0000u), acc.w);
    acc.x = fmaf(w1, __uint_as_float(u1.x << 16), acc.x);
    acc.y = fmaf(w1, __uint_as_float(u1.x & 0xffff0000u), acc.y);
    acc.z = fmaf(w1, __uint_as_float(u1.y << 16), acc.z);
    acc.w = fmaf(w1, __uint_as_float(u1.y & 0xffff0000u), acc.w);
    acc.x = fmaf(w2, __uint_as_float(u2.x << 16), acc.x);
    acc.y = fmaf(w2, __uint_as_float(u2.x & 0xffff0000u), acc.y);
    acc.z = fmaf(w2, __uint_as_float(u2.y << 16), acc.z);
    acc.w = fmaf(w2, __uint_as_float(u2.y & 0xffff0000u), acc.w);
    acc.x = fmaf(w3, __uint_as_float(u3.x << 16), acc.x);
    acc.y = fmaf(w3, __uint_as_float(u3.x & 0xffff0000u), acc.y);
    acc.z = fmaf(w3, __uint_as_float(u3.y << 16), acc.z);
    acc.w = fmaf(w3, __uint_as_float(u3.y & 0xffff0000u), acc.w);
  }
  for (; idx < b1; ++idx) {
    int s0 = s_lds[node][idx];
    float w0 = w_lds[node][idx][h];
    uint2 u0 = F2[(size_t)s0 * 64 + l];
    acc.x = fmaf(w0, __uint_as_float(u0.x << 16), acc.x);
    acc.y = fmaf(w0, __uint_as_float(u0.x & 0xffff0000u), acc.y);
    acc.z = fmaf(w0, __uint_as_float(u0.y << 16), acc.z);
    acc.w = fmaf(w0, __uint_as_float(u0.y & 0xffff0000u), acc.w);
  }
  // fallback for deg > DCAP (recompute w inline; parity-split between waves)
  for (int ix = DCAP + q; ix < deg; ix += 2) {
    int s0 = csr[start + ix];
    float e0 = el[s0 * HEADS + h] + ern;
    e0 = fmaxf(e0, 0.2f * e0);
    float w0 = __expf(e0);
    uint2 u0 = F2[(size_t)s0 * 64 + l];
    acc.x = fmaf(w0, __uint_as_float(u0.x << 16), acc.x);
    acc.y = fmaf(w0, __uint_as_float(u0.x & 0xffff0000u), acc.y);
    acc.z = fmaf(w0, __uint_as_float(u0.y << 16), acc.z);
    acc.w = fmaf(w0, __uint_as_float(u0.y & 0xffff0000u), acc.w);
  }

  // ---- combine wave pair + epilogue ----
  if (q == 1) *(float4*)&acc_lds[node][l][0] = acc;
  __syncthreads();
  if (q == 0 && active) {
    float4 o2 = *(const float4*)&acc_lds[node][l][0];
    acc.x += o2.x; acc.y += o2.y; acc.z += o2.z; acc.w += o2.w;
    float4 b = bias4[l];
    acc.x = fmaf(acc.x, rn, b.x);
    acc.y = fmaf(acc.y, rn, b.y);
    acc.z = fmaf(acc.z, rn, b.z);
    acc.w = fmaf(acc.w, rn, b.w);
    acc.x = acc.x > 0.f ? acc.x : __expf(acc.x) - 1.f;
    acc.y = acc.y > 0.f ? acc.y : __expf(acc.y) - 1.f;
    acc.z = acc.z > 0.f ? acc.z : __expf(acc.z) - 1.f;
    acc.w = acc.w > 0.f ? acc.w : __expf(acc.w) - 1.f;
    ushort4 o;
    o.x = bfcvt(acc.x); o.y = bfcvt(acc.y); o.z = bfcvt(acc.z); o.w = bfcvt(acc.w);
    *(ushort4*)&RstB[(size_t)n * HD + l * 4] = o;
  }
}

// ---------------- final linear: out = RstB @ lin_W + lin_b (MFMA) ----------------
__global__ __launch_bounds__(256) void linear_kernel(
    const ushort* __restrict__ A, const ushort* __restrict__ Lt,
    const float* __restrict__ lin_b, float* __restrict__ out, int N) {
  int t = threadIdx.x;
  int w = t >> 6, l = t & 63;
  int fr = l & 15, g = l >> 4;
  int m0 = blockIdx.x * 64 + w * 16;
  int row = m0 + fr;
  const ushort* arow = A + (size_t)(row < N ? row : 0) * HD;
  floatx4 acc0 = (floatx4)(0.f), acc1 = (floatx4)(0.f);
#pragma unroll
  for (int kf = 0; kf < 8; ++kf) {
    short8 a = *(const short8*)(arow + kf * 32 + g * 8);
    short8 b0 = *(const short8*)(Lt + (size_t)fr * DF + kf * 32 + g * 8);
    short8 b1 = *(const short8*)(Lt + (size_t)(16 + fr) * DF + kf * 32 + g * 8);
    acc0 = __builtin_amdgcn_mfma_f32_16x16x32_bf16(a, b0, acc0, 0, 0, 0);
    acc1 = __builtin_amdgcn_mfma_f32_16x16x32_bf16(a, b1, acc1, 0, 0, 0);
  }
#pragma unroll
  for (int r = 0; r < 4; ++r) {
    int row2 = m0 + g * 4 + r;
    if (row2 < N) {
      out[(size_t)row2 * HIDDEN + fr] = acc0[r] + lin_b[fr];
      out[(size_t)row2 * HIDDEN + 16 + fr] = acc1[r] + lin_b[16 + fr];
    }
  }
}

extern "C" void kernel_launch(void* const* d_in, const int* in_sizes, int n_in,
                              void* d_out, int out_size, void* d_ws, size_t ws_size,
                              hipStream_t stream) {
  const float* x = (const float*)d_in[0];
  const int* src = (const int*)d_in[1];
  const int* dst = (const int*)d_in[2];
  const float* W = (const float*)d_in[3];
  const float* attn_l = (const float*)d_in[4];
  const float* attn_r = (const float*)d_in[5];
  const float* gat_bias = (const float*)d_in[6];
  const float* lin_W = (const float*)d_in[7];
  const float* lin_b = (const float*)d_in[8];
  float* out = (float*)d_out;

  int N = in_sizes[0] / DF;  // 50000
  int E = in_sizes[1];       // 800000

  char* ws = (char*)d_ws;
  size_t off = 0;
  auto walloc = [&](size_t bytes) -> void* {
    void* p = ws + off;
    off += (bytes + 255) & ~(size_t)255;
    return p;
  };
  ushort* Fb = (ushort*)walloc((size_t)N * HD * sizeof(ushort));
  ushort* RstB = (ushort*)walloc((size_t)N * HD * sizeof(ushort));
  ushort* Wt = (ushort*)walloc((size_t)DF * HD * sizeof(ushort));
  ushort* Lt = (ushort*)walloc((size_t)HIDDEN * DF * sizeof(ushort));
  float* el = (float*)walloc((size_t)N * HEADS * sizeof(float));
  float* er = (float*)walloc((size_t)N * HEADS * sizeof(float));
  int* cnt = (int*)walloc((size_t)N * sizeof(int));
  int* cur = (int*)walloc((size_t)N * sizeof(int));
  int* rowptr = (int*)walloc((size_t)(N + 1) * sizeof(int));
  int* csr = (int*)walloc((size_t)E * sizeof(int));
  int* partials = (int*)walloc(256 * sizeof(int));

  hipMemsetAsync(cnt, 0, (size_t)N * sizeof(int), stream);
  hipMemsetAsync(cur, 0, (size_t)N * sizeof(int), stream);

  prep_kernel<<<DF + HIDDEN, 256, 0, stream>>>(W, lin_W, Wt, Lt);
  gemm_mfma_kernel<<<(N + 63) / 64, 256, 0, stream>>>(x, Wt, attn_l, attn_r,
                                                      Fb, el, er, N);
  hist_kernel<<<(E + 255) / 256, 256, 0, stream>>>(dst, cnt, E);
  int nchunks = (N + 1023) / 1024;
  scan1_kernel<<<nchunks, 1024, 0, stream>>>(cnt, rowptr, partials, N);
  scan2_kernel<<<1, 64, 0, stream>>>(partials, rowptr, nchunks, N, E);
  scan3_kernel<<<(N + 255) / 256, 256, 0, stream>>>(rowptr, partials, N);
  fill_kernel<<<(E + 255) / 256, 256, 0, stream>>>(src, dst, rowptr, cur, csr, E);

  int nb2 = (N + 1) / 2;
  aggregate_kernel<<<nb2, 256, 0, stream>>>(
      (const uint2*)Fb, el, er, rowptr, csr, (const float4*)gat_bias, RstB, N);
  linear_kernel<<<(N + 63) / 64, 256, 0, stream>>>(RstB, Lt, lin_b, out, N);
}

// Round 9
// 215.195 us; speedup vs baseline: 1.0155x; 1.0155x over previous
//
#include <hip/hip_runtime.h>
#include <hip/hip_bf16.h>

#define HEADS 8
#define HIDDEN 32
#define DF 256   // D_FEAT
#define HD 256   // HEADS*HIDDEN
#define DCAP 64  // per-node cached-edge cap (Poisson(16) => deg<=64 w.h.p.; fallback covers rest)

typedef __attribute__((ext_vector_type(8))) short short8;
typedef __attribute__((ext_vector_type(4))) float floatx4;

__device__ __forceinline__ ushort bfcvt(float v) {
  return __builtin_bit_cast(ushort, __float2bfloat16(v));
}
__device__ __forceinline__ float bf2f(ushort b) {
  return __uint_as_float(((uint)b) << 16);
}

// ---------------- prep: Wt_bf16[n][k] = bf16(W[k][n]); Lt_bf16[c][k] = bf16(lin_W[k][c]) ----------------
__global__ void prep_kernel(const float* __restrict__ W, const float* __restrict__ lin_W,
                            ushort* __restrict__ Wt, ushort* __restrict__ Lt) {
  int b = blockIdx.x;
  if (b < DF) {
    int k = b, n = threadIdx.x;
    Wt[n * DF + k] = bfcvt(W[k * HD + n]);
  } else {
    int c = b - DF, k = threadIdx.x;
    Lt[c * DF + k] = bfcvt(lin_W[k * HIDDEN + c]);
  }
}

// ---------------- GEMM: Fb(bf16) = x @ W via split-bf16 MFMA, fused el/er ----------------
// BM=64, BN=256, BK=64. 4 waves; wave w: rows mh*32..+31, cols nh*128..+127.
__global__ __launch_bounds__(256) void gemm_mfma_kernel(
    const float* __restrict__ X, const ushort* __restrict__ Wt,
    const float* __restrict__ attn_l, const float* __restrict__ attn_r,
    ushort* __restrict__ Fb, float* __restrict__ el, float* __restrict__ er,
    int M) {
  __shared__ __align__(16) ushort Ahi[64 * 64];
  __shared__ __align__(16) ushort Alo[64 * 64];
  __shared__ __align__(16) ushort Bt[256 * 64];

  int t = threadIdx.x;
  int w = t >> 6, l = t & 63;
  int mh = w & 1, nh = w >> 1;
  int bm = blockIdx.x * 64;

  floatx4 acc[2][8];
#pragma unroll
  for (int i = 0; i < 2; i++)
#pragma unroll
    for (int j = 0; j < 8; j++) acc[i][j] = (floatx4)(0.f);

  for (int k0 = 0; k0 < DF; k0 += 64) {
    // ---- stage A (64 rows x 64 k, f32 -> hi/lo bf16 via hw cvt) ----
#pragma unroll
    for (int q = 0; q < 4; q++) {
      int chunk = q * 256 + t;
      int row = chunk >> 4;
      int c = chunk & 15;
      float4 v;
      if (bm + row < M) v = *(const float4*)(X + (size_t)(bm + row) * DF + k0 + c * 4);
      else v = make_float4(0.f, 0.f, 0.f, 0.f);
      ushort h0 = bfcvt(v.x), h1 = bfcvt(v.y), h2 = bfcvt(v.z), h3 = bfcvt(v.w);
      ushort l0 = bfcvt(v.x - bf2f(h0));
      ushort l1 = bfcvt(v.y - bf2f(h1));
      ushort l2 = bfcvt(v.z - bf2f(h2));
      ushort l3 = bfcvt(v.w - bf2f(h3));
      int s = c >> 1, half = c & 1;
      int off = row * 64 + ((s ^ (row & 7)) << 3) + half * 4;
      ushort4 hv; hv.x = h0; hv.y = h1; hv.z = h2; hv.w = h3;
      ushort4 lv; lv.x = l0; lv.y = l1; lv.z = l2; lv.w = l3;
      *(ushort4*)&Ahi[off] = hv;
      *(ushort4*)&Alo[off] = lv;
    }
    // ---- stage B (256 n-rows x 64 k bf16 from Wt) ----
#pragma unroll
    for (int q = 0; q < 8; q++) {
      int chunk = q * 256 + t;
      int n = chunk >> 3;
      int c = chunk & 7;
      short8 v = *(const short8*)(Wt + (size_t)n * DF + k0 + c * 8);
      *(short8*)&Bt[n * 64 + ((c ^ (n & 7)) << 3)] = v;
    }
    __syncthreads();
    int g = l >> 4;
    int fr = l & 15;
#pragma unroll
    for (int kc = 0; kc < 2; kc++) {
      short8 ah[2], al2[2], bfr[8];
#pragma unroll
      for (int mf = 0; mf < 2; mf++) {
        int row = mh * 32 + mf * 16 + fr;
        int s = (kc * 4 + g) ^ (row & 7);
        ah[mf] = *(const short8*)&Ahi[row * 64 + (s << 3)];
        al2[mf] = *(const short8*)&Alo[row * 64 + (s << 3)];
      }
#pragma unroll
      for (int nf = 0; nf < 8; nf++) {
        int n = nh * 128 + nf * 16 + fr;
        int s = (kc * 4 + g) ^ (n & 7);
        bfr[nf] = *(const short8*)&Bt[n * 64 + (s << 3)];
      }
#pragma unroll
      for (int mf = 0; mf < 2; mf++)
#pragma unroll
        for (int nf = 0; nf < 8; nf++) {
          acc[mf][nf] = __builtin_amdgcn_mfma_f32_16x16x32_bf16(ah[mf], bfr[nf], acc[mf][nf], 0, 0, 0);
          acc[mf][nf] = __builtin_amdgcn_mfma_f32_16x16x32_bf16(al2[mf], bfr[nf], acc[mf][nf], 0, 0, 0);
        }
    }
    __syncthreads();
  }

  int fr = l & 15, fq = l >> 4;
  // ---- fused el/er epilogue: wave covers 4 full heads (nh*4..+3) x 32 rows ----
  {
    float al[8], ar8[8];
#pragma unroll
    for (int nf = 0; nf < 8; ++nf) {
      al[nf] = attn_l[nh * 128 + nf * 16 + fr];
      ar8[nf] = attn_r[nh * 128 + nf * 16 + fr];
    }
#pragma unroll
    for (int mf = 0; mf < 2; ++mf)
#pragma unroll
      for (int r = 0; r < 4; ++r)
#pragma unroll
        for (int p = 0; p < 4; ++p) {
          float vl = acc[mf][2 * p][r] * al[2 * p] + acc[mf][2 * p + 1][r] * al[2 * p + 1];
          float vr = acc[mf][2 * p][r] * ar8[2 * p] + acc[mf][2 * p + 1][r] * ar8[2 * p + 1];
#pragma unroll
          for (int off = 1; off < 16; off <<= 1) {
            vl += __shfl_xor(vl, off, 16);
            vr += __shfl_xor(vr, off, 16);
          }
          int row = bm + mh * 32 + mf * 16 + fq * 4 + r;
          if (fr == 0 && row < M) {
            el[row * HEADS + nh * 4 + p] = vl;
            er[row * HEADS + nh * 4 + p] = vr;
          }
        }
  }
  // ---- C write: col=l&15, row=(l>>4)*4+r ----
#pragma unroll
  for (int mf = 0; mf < 2; mf++) {
#pragma unroll
    for (int nf = 0; nf < 8; nf++) {
      int col = nh * 128 + nf * 16 + fr;
#pragma unroll
      for (int r = 0; r < 4; r++) {
        int row = bm + mh * 32 + mf * 16 + fq * 4 + r;
        if (row < M) Fb[(size_t)row * HD + col] = bfcvt(acc[mf][nf][r]);
      }
    }
  }
}

// ---------------- CSR build ----------------
__global__ void hist_kernel(const int* __restrict__ dst, int* __restrict__ cnt, int E) {
  int e = blockIdx.x * blockDim.x + threadIdx.x;
  if (e < E) atomicAdd(&cnt[dst[e]], 1);
}

__global__ __launch_bounds__(1024) void scan1_kernel(
    const int* __restrict__ cnt, int* __restrict__ rowptr,
    int* __restrict__ partials, int N) {
  __shared__ int buf[1024];
  int b = blockIdx.x, t = threadIdx.x;
  int i = b * 1024 + t;
  int v = (i < N) ? cnt[i] : 0;
  buf[t] = v;
  __syncthreads();
  for (int off = 1; off < 1024; off <<= 1) {
    int x = (t >= off) ? buf[t - off] : 0;
    __syncthreads();
    buf[t] += x;
    __syncthreads();
  }
  int incl = buf[t];
  if (i < N) rowptr[i] = incl - v;  // exclusive
  if (t == 1023) partials[b] = incl;
}

__global__ void scan2_kernel(int* __restrict__ partials, int* __restrict__ rowptr,
                             int nchunks, int N, int E) {
  int t = threadIdx.x;  // 64 threads, 1 block
  if (nchunks <= 64) {
    int v = (t < nchunks) ? partials[t] : 0;
    int incl = v;
#pragma unroll
    for (int off = 1; off < 64; off <<= 1) {
      int x = __shfl_up(incl, off, 64);
      if (t >= off) incl += x;
    }
    if (t < nchunks) partials[t] = incl - v;
  } else if (t == 0) {
    int sum = 0;
    for (int b = 0; b < nchunks; b++) {
      int v = partials[b];
      partials[b] = sum;
      sum += v;
    }
  }
  if (t == 0) rowptr[N] = E;
}

__global__ void scan3_kernel(int* __restrict__ rowptr, const int* __restrict__ partials, int N) {
  int i = blockIdx.x * blockDim.x + threadIdx.x;
  if (i < N) rowptr[i] += partials[i >> 10];
}

__global__ void fill_kernel(const int* __restrict__ src, const int* __restrict__ dst,
                            const int* __restrict__ rowptr, int* __restrict__ cur,
                            int* __restrict__ csr, int E) {
  int e = blockIdx.x * blockDim.x + threadIdx.x;
  if (e < E) {
    int d = dst[e];
    int p = atomicAdd(&cur[d], 1);
    csr[rowptr[d] + p] = src[e];
  }
}

// ---------------- aggregate: softmax + LDS w-cache + bf16 gather (unroll-8) + bias + ELU
//                  + fused final linear (MFMA on wave 0) ----------------
// 1 wave/node, 4 nodes/block. Pass A: h=l>>3, 8 sub-lanes/head. Pass B: lane covers
// cols 4l..4l+3. Epilogue: rst -> LDS (16x264 bf16, rows 4..15 zero), wave 0 does
// [16x256]@[256x32] MFMA (mirrors verified linear_kernel fragment mapping), writes out.
__global__ __launch_bounds__(256) void aggregate_kernel(
    const uint2* __restrict__ F2, const float* __restrict__ el,
    const float* __restrict__ er, const int* __restrict__ rowptr,
    const int* __restrict__ csr, const float4* __restrict__ bias4,
    const ushort* __restrict__ Lt, const float* __restrict__ lin_b,
    float* __restrict__ out, int N) {
  __shared__ float w_lds[4][DCAP][HEADS];
  __shared__ int s_lds[4][DCAP];
  __shared__ __align__(16) ushort rst_lds[16][264];  // padded row: 264*2=528B (16B-mult)
  int wv = threadIdx.x >> 6, l = threadIdx.x & 63;
  int t = threadIdx.x;
  // zero rst rows (only rows 0-3 get overwritten; 4-15 feed MFMA as zeros)
  for (int i = t; i < 16 * 264; i += 256) ((ushort*)rst_lds)[i] = 0;

  int n = blockIdx.x * 4 + wv;
  bool active = (n < N);
  int h = l >> 3, sub = l & 7;
  int start = 0, deg = 0;
  float ern = 0.f;
  if (active) {
    start = rowptr[n];
    deg = rowptr[n + 1] - start;
    ern = er[n * HEADS + h];
  }

  // ---- pass A ----
  float ssum = 0.f;
  for (int idx = sub; idx < deg; idx += 8) {
    int s = csr[start + idx];
    float e = el[s * HEADS + h] + ern;
    e = fmaxf(e, 0.2f * e);  // LeakyReLU(0.2)
    float wgt = __expf(e);   // no max-shift: |e| small for this data, exp-safe
    ssum += wgt;
    if (idx < DCAP) {
      w_lds[wv][idx][h] = wgt;
      if (h == 0) s_lds[wv][idx] = s;
    }
  }
#pragma unroll
  for (int off = 1; off < 8; off <<= 1) ssum += __shfl_xor(ssum, off, 8);
  float rn = (ssum > 0.f) ? 1.0f / ssum : 0.f;
  __syncthreads();  // also orders rst_lds zeroing vs later writes

  // ---- pass B (unroll-8 for deep MLP) ----
  float4 acc = make_float4(0.f, 0.f, 0.f, 0.f);
  int lim = deg < DCAP ? deg : DCAP;
  int idx = 0;
  for (; idx + 8 <= lim; idx += 8) {
    int ss[8]; float ww[8]; uint2 uu[8];
#pragma unroll
    for (int k = 0; k < 8; k++) {
      ss[k] = s_lds[wv][idx + k];
      ww[k] = w_lds[wv][idx + k][h];
    }
#pragma unroll
    for (int k = 0; k < 8; k++) uu[k] = F2[(size_t)ss[k] * 64 + l];
#pragma unroll
    for (int k = 0; k < 8; k++) {
      acc.x = fmaf(ww[k], __uint_as_float(uu[k].x << 16), acc.x);
      acc.y = fmaf(ww[k], __uint_as_float(uu[k].x & 0xffff0000u), acc.y);
      acc.z = fmaf(ww[k], __uint_as_float(uu[k].y << 16), acc.z);
      acc.w = fmaf(ww[k], __uint_as_float(uu[k].y & 0xffff0000u), acc.w);
    }
  }
  for (; idx + 4 <= lim; idx += 4) {
    int ss[4]; float ww[4]; uint2 uu[4];
#pragma unroll
    for (int k = 0; k < 4; k++) {
      ss[k] = s_lds[wv][idx + k];
      ww[k] = w_lds[wv][idx + k][h];
    }
#pragma unroll
    for (int k = 0; k < 4; k++) uu[k] = F2[(size_t)ss[k] * 64 + l];
#pragma unroll
    for (int k = 0; k < 4; k++) {
      acc.x = fmaf(ww[k], __uint_as_float(uu[k].x << 16), acc.x);
      acc.y = fmaf(ww[k], __uint_as_float(uu[k].x & 0xffff0000u), acc.y);
      acc.z = fmaf(ww[k], __uint_as_float(uu[k].y << 16), acc.z);
      acc.w = fmaf(ww[k], __uint_as_float(uu[k].y & 0xffff0000u), acc.w);
    }
  }
  for (; idx < lim; ++idx) {
    int s0 = s_lds[wv][idx];
    float w0 = w_lds[wv][idx][h];
    uint2 u0 = F2[(size_t)s0 * 64 + l];
    acc.x = fmaf(w0, __uint_as_float(u0.x << 16), acc.x);
    acc.y = fmaf(w0, __uint_as_float(u0.x & 0xffff0000u), acc.y);
    acc.z = fmaf(w0, __uint_as_float(u0.y << 16), acc.z);
    acc.w = fmaf(w0, __uint_as_float(u0.y & 0xffff0000u), acc.w);
  }
  // fallback for deg > DCAP (recompute w inline; rare/never for this data)
  for (; idx < deg; ++idx) {
    int s0 = csr[start + idx];
    float e0 = el[s0 * HEADS + h] + ern;
    e0 = fmaxf(e0, 0.2f * e0);
    float w0 = __expf(e0);
    uint2 u0 = F2[(size_t)s0 * 64 + l];
    acc.x = fmaf(w0, __uint_as_float(u0.x << 16), acc.x);
    acc.y = fmaf(w0, __uint_as_float(u0.x & 0xffff0000u), acc.y);
    acc.z = fmaf(w0, __uint_as_float(u0.y << 16), acc.z);
    acc.w = fmaf(w0, __uint_as_float(u0.y & 0xffff0000u), acc.w);
  }

  if (active) {
    float4 b = bias4[l];
    acc.x = fmaf(acc.x, rn, b.x);
    acc.y = fmaf(acc.y, rn, b.y);
    acc.z = fmaf(acc.z, rn, b.z);
    acc.w = fmaf(acc.w, rn, b.w);
    acc.x = acc.x > 0.f ? acc.x : __expf(acc.x) - 1.f;
    acc.y = acc.y > 0.f ? acc.y : __expf(acc.y) - 1.f;
    acc.z = acc.z > 0.f ? acc.z : __expf(acc.z) - 1.f;
    acc.w = acc.w > 0.f ? acc.w : __expf(acc.w) - 1.f;
    ushort4 o;
    o.x = bfcvt(acc.x); o.y = bfcvt(acc.y); o.z = bfcvt(acc.z); o.w = bfcvt(acc.w);
    *(ushort4*)&rst_lds[wv][l * 4] = o;
  }
  __syncthreads();

  // ---- fused final linear on wave 0: out[4x32] = rst[4x256] @ lin_W + lin_b ----
  if (wv == 0) {
    int fr = l & 15, g = l >> 4;
    floatx4 a0 = (floatx4)(0.f), a1 = (floatx4)(0.f);
#pragma unroll
    for (int kf = 0; kf < 8; ++kf) {
      short8 a = *(const short8*)&rst_lds[fr][kf * 32 + g * 8];
      short8 b0 = *(const short8*)(Lt + (size_t)fr * DF + kf * 32 + g * 8);
      short8 b1 = *(const short8*)(Lt + (size_t)(16 + fr) * DF + kf * 32 + g * 8);
      a0 = __builtin_amdgcn_mfma_f32_16x16x32_bf16(a, b0, a0, 0, 0, 0);
      a1 = __builtin_amdgcn_mfma_f32_16x16x32_bf16(a, b1, a1, 0, 0, 0);
    }
#pragma unroll
    for (int r = 0; r < 4; ++r) {
      int row = g * 4 + r;           // 0..15; only 0..3 are real nodes
      int n2 = blockIdx.x * 4 + row;
      if (row < 4 && n2 < N) {
        out[(size_t)n2 * HIDDEN + fr] = a0[r] + lin_b[fr];
        out[(size_t)n2 * HIDDEN + 16 + fr] = a1[r] + lin_b[16 + fr];
      }
    }
  }
}

extern "C" void kernel_launch(void* const* d_in, const int* in_sizes, int n_in,
                              void* d_out, int out_size, void* d_ws, size_t ws_size,
                              hipStream_t stream) {
  const float* x = (const float*)d_in[0];
  const int* src = (const int*)d_in[1];
  const int* dst = (const int*)d_in[2];
  const float* W = (const float*)d_in[3];
  const float* attn_l = (const float*)d_in[4];
  const float* attn_r = (const float*)d_in[5];
  const float* gat_bias = (const float*)d_in[6];
  const float* lin_W = (const float*)d_in[7];
  const float* lin_b = (const float*)d_in[8];
  float* out = (float*)d_out;

  int N = in_sizes[0] / DF;  // 50000
  int E = in_sizes[1];       // 800000

  char* ws = (char*)d_ws;
  size_t off = 0;
  auto walloc = [&](size_t bytes) -> void* {
    void* p = ws + off;
    off += (bytes + 255) & ~(size_t)255;
    return p;
  };
  ushort* Fb = (ushort*)walloc((size_t)N * HD * sizeof(ushort));
  ushort* Wt = (ushort*)walloc((size_t)DF * HD * sizeof(ushort));
  ushort* Lt = (ushort*)walloc((size_t)HIDDEN * DF * sizeof(ushort));
  float* el = (float*)walloc((size_t)N * HEADS * sizeof(float));
  float* er = (float*)walloc((size_t)N * HEADS * sizeof(float));
  int* cnt = (int*)walloc((size_t)N * sizeof(int));
  int* cur = (int*)walloc((size_t)N * sizeof(int));
  int* rowptr = (int*)walloc((size_t)(N + 1) * sizeof(int));
  int* csr = (int*)walloc((size_t)E * sizeof(int));
  int* partials = (int*)walloc(256 * sizeof(int));

  hipMemsetAsync(cnt, 0, (size_t)N * sizeof(int), stream);
  hipMemsetAsync(cur, 0, (size_t)N * sizeof(int), stream);

  prep_kernel<<<DF + HIDDEN, 256, 0, stream>>>(W, lin_W, Wt, Lt);
  gemm_mfma_kernel<<<(N + 63) / 64, 256, 0, stream>>>(x, Wt, attn_l, attn_r,
                                                      Fb, el, er, N);
  hist_kernel<<<(E + 255) / 256, 256, 0, stream>>>(dst, cnt, E);
  int nchunks = (N + 1023) / 1024;
  scan1_kernel<<<nchunks, 1024, 0, stream>>>(cnt, rowptr, partials, N);
  scan2_kernel<<<1, 64, 0, stream>>>(partials, rowptr, nchunks, N, E);
  scan3_kernel<<<(N + 255) / 256, 256, 0, stream>>>(rowptr, partials, N);
  fill_kernel<<<(E + 255) / 256, 256, 0, stream>>>(src, dst, rowptr, cur, csr, E);

  int nb4 = (N + 3) / 4;
  aggregate_kernel<<<nb4, 256, 0, stream>>>(
      (const uint2*)Fb, el, er, rowptr, csr, (const float4*)gat_bias,
      Lt, lin_b, out, N);
}